// Round 2
// baseline (1096.418 us; speedup 1.0000x reference)
//
// CentroidLayer (Karcher-flow centroid update) — MI355X fp32 implementation.
//
// R2 (vs R1): stage_a uses libm cosf for quadrature (accuracy); stage_b LDS
// cut 40KB -> 32KB via ping-pong slots for the Chebyshev recurrence
// (occupancy 4 -> 5 WG/CU). Core algorithm unchanged:
//  - stage_a: per group g (32): C^{-1/2}, C^{+1/2} via Chebyshev polys of
//    1/(sqrt(x)+1e-9) and sqrt(x) on [0.45, ||C||inf*1.02] (Clenshaw, coeffs
//    by 64-node Chebyshev quadrature). Stores aC[g] = 0.48/||C||inf, a
//    rigorous eig(M) lower bound (X >= 0.5 I by construction).
//  - stage_b: 32768 jobs (1024 samples x 32 groups): M = Cm05*X*Cm05 (SPD),
//    log(M) as degree-29 Chebyshev series, closed-form coeffs
//    c_k = -2(-z)^k/k on per-job [aC, ||M||inf], Paterson-Stockmeyer folding
//    (T_{6j+i} = 2 T_i T_{6j} - T_{6j-i}) => 14 matmuls/job. Deterministic
//    per-WG partial sums (no atomics).
//  - stage_c: L_m = eta*mean(log); E = matfun(L_m, exp) = sign(L)*exp(|L|):
//    K = sign(L_m) via 28 Newton-Schulz iters, E = K*expm(K*L_m) (4-term
//    Taylor, ||K L_m|| <= ~0.02). C_new = Cp05 * (E * Cp05).
//  - Matmul micro-kernel: 1 wave per 32x32 job, operands in LDS, lane
//    (lr,lc) owns a 4x4 tile; A operands are symmetric so both fragment
//    loads are contiguous ds_read_b128 with 8-way broadcast (conflict-free).

#include <hip/hip_runtime.h>
#include <math.h>

#define DEV static __device__ __forceinline__

namespace {

constexpr int    MSZ   = 1024;           // 32*32
constexpr int    NGRP  = 32;             // CLS*N
constexpr int    NB    = 1024;           // sampled batch count
constexpr int    NJPW  = 32;             // jobs per stage_b workgroup
constexpr int    NWGB  = NGRP * (NB / NJPW);   // 1024
constexpr int    XROW  = NGRP * MSZ;     // 32768 floats per batch row of X

// ws layout (float offsets)
constexpr size_t WS_CM05 = 0;                      // [32][1024]
constexpr size_t WS_CP05 = WS_CM05 + NGRP * MSZ;   // [32][1024]
constexpr size_t WS_AC   = WS_CP05 + NGRP * MSZ;   // [32]
constexpr size_t WS_PART = 131072;                 // [1024][1024]

static_assert(NWGB == 1024, "grid assumption");

// C[r0+i][c0+j] = sum_k A[r0+i][k]*B[k][c0+j]; A is read transposed-via-symmetry
// (A[r][k] == A[k][r]), so both fragment loads are contiguous float4 in row k.
DEV void mm32(const float* A, const float* B, int r0, int c0, float acc[4][4]) {
#pragma unroll
  for (int i = 0; i < 4; ++i)
#pragma unroll
    for (int j = 0; j < 4; ++j) acc[i][j] = 0.0f;
#pragma unroll 8
  for (int k = 0; k < 32; ++k) {
    const float4 av = *(const float4*)(A + (k << 5) + r0);
    const float4 bv = *(const float4*)(B + (k << 5) + c0);
    const float a[4] = {av.x, av.y, av.z, av.w};
    const float b[4] = {bv.x, bv.y, bv.z, bv.w};
#pragma unroll
    for (int i = 0; i < 4; ++i)
#pragma unroll
      for (int j = 0; j < 4; ++j) acc[i][j] = fmaf(a[i], b[j], acc[i][j]);
  }
}

DEV void twrite(float* D, int r0, int c0, const float t[4][4]) {
#pragma unroll
  for (int i = 0; i < 4; ++i) {
    float4 v;
    v.x = t[i][0]; v.y = t[i][1]; v.z = t[i][2]; v.w = t[i][3];
    *(float4*)(D + ((r0 + i) << 5) + c0) = v;
  }
}

DEV void tread(const float* M, int r0, int c0, float t[4][4]) {
#pragma unroll
  for (int i = 0; i < 4; ++i) {
    const float4 v = *(const float4*)(M + ((r0 + i) << 5) + c0);
    t[i][0] = v.x; t[i][1] = v.y; t[i][2] = v.z; t[i][3] = v.w;
  }
}

DEV void taccum(float S[4][4], const float a[4][4]) {
#pragma unroll
  for (int i = 0; i < 4; ++i)
#pragma unroll
    for (int j = 0; j < 4; ++j) S[i][j] += a[i][j];
}

DEV float wsum(float v) {
#pragma unroll
  for (int m = 1; m < 64; m <<= 1) v += __shfl_xor(v, m);
  return v;
}

DEV void g2l_mat(float* dst, const float* src, int lane) {
#pragma unroll
  for (int q = 0; q < 4; ++q) {
    const int off = q * 256 + lane * 4;
    *(float4*)(dst + off) = *(const float4*)(src + off);
  }
}

}  // namespace

// ---------------------------------------------------------------------------
// stage_a: per-group C^{-1/2}, C^{+1/2}, and eig(M) lower bound aC.
// ---------------------------------------------------------------------------
__global__ void __launch_bounds__(64, 1)
centroid_stage_a(const float* __restrict__ Cin, float* __restrict__ ws) {
  __shared__ float lds[4 * MSZ];
  __shared__ float coefs[2][21];
  float* CM = lds;
  float* TT = lds + MSZ;
  float* B1 = lds + 2 * MSZ;
  float* B2 = lds + 3 * MSZ;

  const int lane = threadIdx.x;
  const int lr = lane >> 3, lc = lane & 7;
  const int r0 = lr << 2, c0 = lc << 2;
  const bool dg = (lr == lc);
  const int g = blockIdx.x;

  g2l_mat(CM, Cin + (size_t)g * MSZ, lane);
  __syncthreads();

  // ||C||inf (>= lambda_max for symmetric C)
  float tC[4][4];
  tread(CM, r0, c0, tC);
  float rs[4];
#pragma unroll
  for (int i = 0; i < 4; ++i)
    rs[i] = fabsf(tC[i][0]) + fabsf(tC[i][1]) + fabsf(tC[i][2]) + fabsf(tC[i][3]);
#pragma unroll
  for (int m = 1; m < 8; m <<= 1) {
#pragma unroll
    for (int i = 0; i < 4; ++i) rs[i] += __shfl_xor(rs[i], m);
  }
  float mx = fmaxf(fmaxf(rs[0], rs[1]), fmaxf(rs[2], rs[3]));
#pragma unroll
  for (int m = 8; m < 64; m <<= 1) mx = fmaxf(mx, __shfl_xor(mx, m));

  const float aR = 0.45f;           // lambda_min(C) >= 0.5 by construction
  const float bR = mx * 1.02f;
  const float alpha = 0.5f * (aR + bR), beta = 0.5f * (bR - aR);

  if (lane == 0) ws[WS_AC + g] = 0.48f / bR;  // rigorous lower bound for eig(M)

  // Chebyshev coefficients of f on [aR,bR] by 64-node quadrature (libm cosf
  // for accuracy — args reach ~63 rad, __cosf range reduction is too sloppy).
  const float theta = ((float)lane + 0.5f) * (3.14159265358979323846f / 64.0f);
  const float xn = alpha + beta * cosf(theta);
  const float sq = sqrtf(xn);
  const float f1 = 1.0f / (sq + 1e-9f);  // -> Cm05   (matches ref's eps)
  const float f2 = sq;                   // -> Cp05
  for (int k = 0; k <= 20; ++k) {
    const float ck = cosf((float)k * theta);
    const float s1 = wsum(f1 * ck);
    const float s2 = wsum(f2 * ck);
    if (lane == 0) {
      const float sc = (k == 0) ? (1.0f / 64.0f) : (2.0f / 64.0f);
      coefs[0][k] = s1 * sc;
      coefs[1][k] = s2 * sc;
    }
  }

  // TT = (C - alpha I)/beta
  {
    const float invb = 1.0f / beta;
    float t[4][4];
#pragma unroll
    for (int i = 0; i < 4; ++i)
#pragma unroll
      for (int j = 0; j < 4; ++j) {
        float v = tC[i][j];
        if (dg && i == j) v -= alpha;
        t[i][j] = v * invb;
      }
    twrite(TT, r0, c0, t);
  }
  __syncthreads();

  // Two Clenshaw evaluations (degree 20)
  for (int f = 0; f < 2; ++f) {
    const float* cf = coefs[f];
    {
      float tI[4][4], tZ[4][4];
#pragma unroll
      for (int i = 0; i < 4; ++i)
#pragma unroll
        for (int j = 0; j < 4; ++j) {
          tI[i][j] = (dg && i == j) ? cf[20] : 0.0f;
          tZ[i][j] = 0.0f;
        }
      twrite(B1, r0, c0, tI);
      twrite(B2, r0, c0, tZ);
    }
    __syncthreads();
    float* cur = B1;
    float* prev = B2;
    for (int k = 19; k >= 1; --k) {
      float acc[4][4];
      mm32(TT, cur, r0, c0, acc);
      const float ck = cf[k];
      float pt[4][4];
      tread(prev, r0, c0, pt);
      float nt[4][4];
#pragma unroll
      for (int i = 0; i < 4; ++i)
#pragma unroll
        for (int j = 0; j < 4; ++j) {
          float v = 2.0f * acc[i][j] - pt[i][j];
          if (dg && i == j) v += ck;
          nt[i][j] = v;
        }
      __syncthreads();
      twrite(prev, r0, c0, nt);
      __syncthreads();
      float* tmp = cur; cur = prev; prev = tmp;
    }
    float acc[4][4];
    mm32(TT, cur, r0, c0, acc);
    float pt[4][4];
    tread(prev, r0, c0, pt);
    float* dst = ws + ((f == 0) ? WS_CM05 : WS_CP05) + (size_t)g * MSZ;
#pragma unroll
    for (int i = 0; i < 4; ++i) {
      float4 v4;
      float vv[4];
#pragma unroll
      for (int j = 0; j < 4; ++j) {
        float v = acc[i][j] - pt[i][j];
        if (dg && i == j) v += cf[0];
        vv[j] = v;
      }
      v4.x = vv[0]; v4.y = vv[1]; v4.z = vv[2]; v4.w = vv[3];
      *(float4*)(dst + ((r0 + i) << 5) + c0) = v4;
    }
    __syncthreads();
  }
}

// ---------------------------------------------------------------------------
// stage_b: 1024 WGs x 32 jobs: sum of log(Cm05 X_b Cm05) per group chunk.
// LDS slots (8 x 4KB = 32KB -> 5 WG/CU):
//   CM (Cm05) | SXs (X, later T18) | SVs (V, later H_j) | T1s | P0 (T2/T4)
//   | P1 (T3/T5) | T6s | S1 (T12/T24)
// The recurrence T_{k+1} = 2 T1 T_k - T_{k-1} needs T_{k-1} only in registers
// (T2t..T5t are kept there for the H_j combinations anyway), so T2..T5
// ping-pong through P0/P1.
// ---------------------------------------------------------------------------
__global__ void __launch_bounds__(64, 1)
centroid_stage_b(const float* __restrict__ X, const int* __restrict__ idx,
                 const float* __restrict__ ws, float* __restrict__ partials) {
  __shared__ float lds[8 * MSZ];  // 32 KB
  float* CM  = lds;
  float* SXs = lds + MSZ;       // X tile; later T18 slot
  float* SVs = lds + 2 * MSZ;   // V; later H
  float* T1s = lds + 3 * MSZ;
  float* P0  = lds + 4 * MSZ;   // T2 / T4
  float* P1  = lds + 5 * MSZ;   // T3 / T5
  float* T6s = lds + 6 * MSZ;
  float* S1  = lds + 7 * MSZ;   // T12 / T24

  const int lane = threadIdx.x;
  const int lr = lane >> 3, lc = lane & 7;
  const int r0 = lr << 2, c0 = lc << 2;
  const bool dg = (lr == lc);

  const int w = blockIdx.x;
  const int g = w >> 5;
  const int b0 = (w & 31) * NJPW;

  g2l_mat(CM, ws + WS_CM05 + (size_t)g * MSZ, lane);
  const float aB = ws[WS_AC + g];
  __syncthreads();

  float S[4][4];
#pragma unroll
  for (int i = 0; i < 4; ++i)
#pragma unroll
    for (int j = 0; j < 4; ++j) S[i][j] = 0.0f;

  for (int jb = 0; jb < NJPW; ++jb) {
    const int bi = idx[b0 + jb];
    g2l_mat(SXs, X + (size_t)bi * XROW + (size_t)g * MSZ, lane);
    __syncthreads();

    float acc[4][4];

    // V = X * Cm05
    mm32(SXs, CM, r0, c0, acc);
    twrite(SVs, r0, c0, acc);
    __syncthreads();

    // M = Cm05 * V  (SPD); range + coefficients + T1
    mm32(CM, SVs, r0, c0, acc);

    float rs[4];
#pragma unroll
    for (int i = 0; i < 4; ++i)
      rs[i] = fabsf(acc[i][0]) + fabsf(acc[i][1]) + fabsf(acc[i][2]) + fabsf(acc[i][3]);
#pragma unroll
    for (int m = 1; m < 8; m <<= 1) {
#pragma unroll
      for (int i = 0; i < 4; ++i) rs[i] += __shfl_xor(rs[i], m);
    }
    float mxv = fmaxf(fmaxf(rs[0], rs[1]), fmaxf(rs[2], rs[3]));
#pragma unroll
    for (int m = 8; m < 64; m <<= 1) mxv = fmaxf(mxv, __shfl_xor(mxv, m));
    const float bB = mxv * 1.001f + 1e-6f;  // ||M||inf >= lambda_max

    const float alpha = 0.5f * (aB + bB);
    const float beta = 0.5f * (bB - aB);
    const float wq = beta / alpha;
    const float zq = wq / (1.0f + sqrtf(fmaxf(1.0f - wq * wq, 0.0f)));

    // closed-form Chebyshev coeffs of log on [aB,bB]; fold for PS scheme
    float cp[30];
    cp[0] = logf(alpha) - log1pf(zq * zq);
    {
      const float tz = -zq;
      float tp = tz;
#pragma unroll
      for (int k = 1; k < 30; ++k) {
        cp[k] = -2.0f * tp * (1.0f / (float)k);
        tp *= tz;
      }
    }
#pragma unroll
    for (int j = 4; j >= 1; --j) {
#pragma unroll
      for (int i = 1; i <= 5; ++i) cp[6 * j - i] -= cp[6 * j + i];
    }

    const float invb = 1.0f / beta;
    float T1t[4][4], T2t[4][4], T3t[4][4], T4t[4][4], T5t[4][4], T6t[4][4], T12t[4][4];

    // T1 = (M - alpha I)/beta ; S += cp0*I + cp1*T1
#pragma unroll
    for (int i = 0; i < 4; ++i)
#pragma unroll
      for (int j = 0; j < 4; ++j) {
        float v = acc[i][j];
        if (dg && i == j) v -= alpha;
        v *= invb;
        T1t[i][j] = v;
        S[i][j] += cp[1] * v;
        if (dg && i == j) S[i][j] += cp[0];
      }
    twrite(T1s, r0, c0, T1t);
    __syncthreads();

    // T2 = 2 T1*T1 - I  -> P0
    mm32(T1s, T1s, r0, c0, acc);
#pragma unroll
    for (int i = 0; i < 4; ++i)
#pragma unroll
      for (int j = 0; j < 4; ++j) {
        float v = 2.0f * acc[i][j] - ((dg && i == j) ? 1.0f : 0.0f);
        T2t[i][j] = v;
        S[i][j] += cp[2] * v;
      }
    twrite(P0, r0, c0, T2t);
    __syncthreads();

    // T3 = 2 T1*T2 - T1  -> P1
    mm32(T1s, P0, r0, c0, acc);
#pragma unroll
    for (int i = 0; i < 4; ++i)
#pragma unroll
      for (int j = 0; j < 4; ++j) {
        float v = 2.0f * acc[i][j] - T1t[i][j];
        T3t[i][j] = v;
        S[i][j] += cp[3] * v;
      }
    twrite(P1, r0, c0, T3t);
    __syncthreads();

    // T4 = 2 T1*T3 - T2  -> P0 (T2 lives on in registers)
    mm32(T1s, P1, r0, c0, acc);
#pragma unroll
    for (int i = 0; i < 4; ++i)
#pragma unroll
      for (int j = 0; j < 4; ++j) {
        float v = 2.0f * acc[i][j] - T2t[i][j];
        T4t[i][j] = v;
        S[i][j] += cp[4] * v;
      }
    twrite(P0, r0, c0, T4t);
    __syncthreads();

    // T5 = 2 T1*T4 - T3  -> P1
    mm32(T1s, P0, r0, c0, acc);
#pragma unroll
    for (int i = 0; i < 4; ++i)
#pragma unroll
      for (int j = 0; j < 4; ++j) {
        float v = 2.0f * acc[i][j] - T3t[i][j];
        T5t[i][j] = v;
        S[i][j] += cp[5] * v;
      }
    twrite(P1, r0, c0, T5t);
    __syncthreads();

    // T6 = 2 T1*T5 - T4  -> T6s
    mm32(T1s, P1, r0, c0, acc);
#pragma unroll
    for (int i = 0; i < 4; ++i)
#pragma unroll
      for (int j = 0; j < 4; ++j) {
        float v = 2.0f * acc[i][j] - T4t[i][j];
        T6t[i][j] = v;
        S[i][j] += cp[6] * v;
      }
    twrite(T6s, r0, c0, T6t);
    __syncthreads();

    // ---- j=1: H1; S += T6*H1; T12 = 2 T6*T6 - I -> S1
    {
      float h[4][4];
#pragma unroll
      for (int i = 0; i < 4; ++i)
#pragma unroll
        for (int j = 0; j < 4; ++j)
          h[i][j] = 2.0f * (cp[7] * T1t[i][j] + cp[8] * T2t[i][j] + cp[9] * T3t[i][j] +
                            cp[10] * T4t[i][j] + cp[11] * T5t[i][j]);
      twrite(SVs, r0, c0, h);
    }
    __syncthreads();
    mm32(T6s, SVs, r0, c0, acc);
    taccum(S, acc);
    mm32(T6s, T6s, r0, c0, acc);
#pragma unroll
    for (int i = 0; i < 4; ++i)
#pragma unroll
      for (int j = 0; j < 4; ++j) {
        float v = 2.0f * acc[i][j] - ((dg && i == j) ? 1.0f : 0.0f);
        T12t[i][j] = v;
        S[i][j] += cp[12] * v;
      }
    twrite(S1, r0, c0, T12t);
    __syncthreads();

    // ---- j=2: H2; S += T12*H2; T18 = 2 T6*T12 - T6 -> SXs
    {
      float h[4][4];
#pragma unroll
      for (int i = 0; i < 4; ++i)
#pragma unroll
        for (int j = 0; j < 4; ++j)
          h[i][j] = 2.0f * (cp[13] * T1t[i][j] + cp[14] * T2t[i][j] + cp[15] * T3t[i][j] +
                            cp[16] * T4t[i][j] + cp[17] * T5t[i][j]);
      twrite(SVs, r0, c0, h);
    }
    __syncthreads();
    mm32(S1, SVs, r0, c0, acc);
    taccum(S, acc);
    mm32(T6s, S1, r0, c0, acc);
    {
      float v2[4][4];
#pragma unroll
      for (int i = 0; i < 4; ++i)
#pragma unroll
        for (int j = 0; j < 4; ++j) {
          float v = 2.0f * acc[i][j] - T6t[i][j];
          v2[i][j] = v;
          S[i][j] += cp[18] * v;
        }
      twrite(SXs, r0, c0, v2);
    }
    __syncthreads();

    // ---- j=3: H3; S += T18*H3; T24 = 2 T6*T18 - T12 -> S1
    {
      float h[4][4];
#pragma unroll
      for (int i = 0; i < 4; ++i)
#pragma unroll
        for (int j = 0; j < 4; ++j)
          h[i][j] = 2.0f * (cp[19] * T1t[i][j] + cp[20] * T2t[i][j] + cp[21] * T3t[i][j] +
                            cp[22] * T4t[i][j] + cp[23] * T5t[i][j]);
      twrite(SVs, r0, c0, h);
    }
    __syncthreads();
    mm32(SXs, SVs, r0, c0, acc);
    taccum(S, acc);
    mm32(T6s, SXs, r0, c0, acc);
    {
      float v2[4][4];
#pragma unroll
      for (int i = 0; i < 4; ++i)
#pragma unroll
        for (int j = 0; j < 4; ++j) {
          float v = 2.0f * acc[i][j] - T12t[i][j];
          v2[i][j] = v;
          S[i][j] += cp[24] * v;
        }
      twrite(S1, r0, c0, v2);
    }
    __syncthreads();

    // ---- j=4: H4; S += T24*H4
    {
      float h[4][4];
#pragma unroll
      for (int i = 0; i < 4; ++i)
#pragma unroll
        for (int j = 0; j < 4; ++j)
          h[i][j] = 2.0f * (cp[25] * T1t[i][j] + cp[26] * T2t[i][j] + cp[27] * T3t[i][j] +
                            cp[28] * T4t[i][j] + cp[29] * T5t[i][j]);
      twrite(SVs, r0, c0, h);
    }
    __syncthreads();
    mm32(S1, SVs, r0, c0, acc);
    taccum(S, acc);
    __syncthreads();
  }

  // partial sum out (deterministic reduction in stage_c)
  {
    float* dst = partials + (size_t)w * MSZ;
#pragma unroll
    for (int i = 0; i < 4; ++i) {
      float4 v4;
      v4.x = S[i][0]; v4.y = S[i][1]; v4.z = S[i][2]; v4.w = S[i][3];
      *(float4*)(dst + ((r0 + i) << 5) + c0) = v4;
    }
  }
}

// ---------------------------------------------------------------------------
// stage_c: per group: L_m; K=sign(L_m) (Newton-Schulz); E=K*exp(K L_m);
//          C_new = Cp05 * (E * Cp05).
// ---------------------------------------------------------------------------
__global__ void __launch_bounds__(64, 1)
centroid_stage_c(const float* __restrict__ ws, float* __restrict__ out) {
  __shared__ float lds[5 * MSZ];
  float* Lm = lds;
  float* Ss = lds + MSZ;
  float* Ts = lds + 2 * MSZ;
  float* Us = lds + 3 * MSZ;
  float* Wsl = lds + 4 * MSZ;

  const int lane = threadIdx.x;
  const int lr = lane >> 3, lc = lane & 7;
  const int r0 = lr << 2, c0 = lc << 2;
  const bool dg = (lr == lc);
  const int g = blockIdx.x;

  // L_m = (eta/NB) * sum of partials
  float t[4][4];
#pragma unroll
  for (int i = 0; i < 4; ++i)
#pragma unroll
    for (int j = 0; j < 4; ++j) t[i][j] = 0.0f;
  for (int p = 0; p < 32; ++p) {
    const float* src = ws + WS_PART + (size_t)(g * 32 + p) * MSZ;
#pragma unroll
    for (int i = 0; i < 4; ++i) {
      const float4 v = *(const float4*)(src + ((r0 + i) << 5) + c0);
      t[i][0] += v.x; t[i][1] += v.y; t[i][2] += v.z; t[i][3] += v.w;
    }
  }
  const float scl = 0.01f / 1024.0f;
#pragma unroll
  for (int i = 0; i < 4; ++i)
#pragma unroll
    for (int j = 0; j < 4; ++j) t[i][j] *= scl;
  twrite(Lm, r0, c0, t);

  float ss = 0.0f;
#pragma unroll
  for (int i = 0; i < 4; ++i)
#pragma unroll
    for (int j = 0; j < 4; ++j) ss += t[i][j] * t[i][j];
  ss = wsum(ss);
  const float innrm = 1.0f / fmaxf(sqrtf(ss), 1e-30f);
  {
    float st[4][4];
#pragma unroll
    for (int i = 0; i < 4; ++i)
#pragma unroll
      for (int j = 0; j < 4; ++j) st[i][j] = t[i][j] * innrm;
    twrite(Ss, r0, c0, st);
  }
  __syncthreads();

  float acc[4][4];

  // Newton-Schulz sign iterations: S <- 1.5 S - 0.5 S^3
  for (int it = 0; it < 28; ++it) {
    mm32(Ss, Ss, r0, c0, acc);
    twrite(Ts, r0, c0, acc);
    __syncthreads();
    mm32(Ts, Ss, r0, c0, acc);
    float st[4][4], sn[4][4];
    tread(Ss, r0, c0, st);
#pragma unroll
    for (int i = 0; i < 4; ++i)
#pragma unroll
      for (int j = 0; j < 4; ++j) sn[i][j] = 1.5f * st[i][j] - 0.5f * acc[i][j];
    __syncthreads();
    twrite(Ss, r0, c0, sn);
    __syncthreads();
  }

  // B = K * Lm
  float bt[4][4];
  mm32(Ss, Lm, r0, c0, acc);
#pragma unroll
  for (int i = 0; i < 4; ++i)
#pragma unroll
    for (int j = 0; j < 4; ++j) bt[i][j] = acc[i][j];
  twrite(Ts, r0, c0, acc);
  __syncthreads();

  // E2 = B*B ; inner = 0.5I + B/6 + E2/24
  mm32(Ts, Ts, r0, c0, acc);
  twrite(Wsl, r0, c0, acc);
  {
    float in4[4][4];
#pragma unroll
    for (int i = 0; i < 4; ++i)
#pragma unroll
      for (int j = 0; j < 4; ++j) {
        float v = bt[i][j] * (1.0f / 6.0f) + acc[i][j] * (1.0f / 24.0f);
        if (dg && i == j) v += 0.5f;
        in4[i][j] = v;
      }
    twrite(Us, r0, c0, in4);
  }
  __syncthreads();

  // poly = I + B + E2*inner
  mm32(Wsl, Us, r0, c0, acc);
  {
    float pl[4][4];
#pragma unroll
    for (int i = 0; i < 4; ++i)
#pragma unroll
      for (int j = 0; j < 4; ++j) {
        float v = bt[i][j] + acc[i][j];
        if (dg && i == j) v += 1.0f;
        pl[i][j] = v;
      }
    __syncthreads();
    twrite(Us, r0, c0, pl);
  }
  __syncthreads();

  // E = K * poly -> Wsl
  mm32(Ss, Us, r0, c0, acc);
  __syncthreads();
  twrite(Wsl, r0, c0, acc);
  __syncthreads();

  // Cp05 -> Ts
  g2l_mat(Ts, ws + WS_CP05 + (size_t)g * MSZ, lane);
  __syncthreads();

  // Z = E * Cp05 -> Us
  mm32(Wsl, Ts, r0, c0, acc);
  __syncthreads();
  twrite(Us, r0, c0, acc);
  __syncthreads();

  // C_new = Cp05 * Z -> out
  mm32(Ts, Us, r0, c0, acc);
  {
    float* dst = out + (size_t)g * MSZ;
#pragma unroll
    for (int i = 0; i < 4; ++i) {
      float4 v4;
      v4.x = acc[i][0]; v4.y = acc[i][1]; v4.z = acc[i][2]; v4.w = acc[i][3];
      *(float4*)(dst + ((r0 + i) << 5) + c0) = v4;
    }
  }
}

extern "C" void kernel_launch(void* const* d_in, const int* in_sizes, int n_in,
                              void* d_out, int out_size, void* d_ws, size_t ws_size,
                              hipStream_t stream) {
  (void)in_sizes; (void)n_in; (void)out_size; (void)ws_size;
  const float* X = (const float*)d_in[0];
  const float* C = (const float*)d_in[1];
  const int* idx = (const int*)d_in[2];
  float* out = (float*)d_out;
  float* ws = (float*)d_ws;

  hipLaunchKernelGGL(centroid_stage_a, dim3(NGRP), dim3(64), 0, stream, C, ws);
  hipLaunchKernelGGL(centroid_stage_b, dim3(NWGB), dim3(64), 0, stream, X, idx, ws,
                     ws + WS_PART);
  hipLaunchKernelGGL(centroid_stage_c, dim3(NGRP), dim3(64), 0, stream, ws, out);
}